// Round 1
// baseline (19802.423 us; speedup 1.0000x reference)
//
#include <hip/hip_runtime.h>
#include <hip/hip_bf16.h>
#include <stdint.h>

typedef unsigned short u16;
typedef unsigned int   u32;
typedef unsigned long long u64;
typedef __attribute__((ext_vector_type(8))) short short8;
typedef __attribute__((ext_vector_type(4))) float f32x4;

#define T_SEQ 2048
#define NTOK  16384        // B*T = 8*2048
#define NGATE 4096         // 2 dirs * 4H(=2048)
#define PBLK  32           // blocks per direction in the scan
#define FSTR  16           // flag stride in ints (64B lines)

__device__ __forceinline__ u16 f2bf(float f) {
    u32 u = __builtin_bit_cast(u32, f);
    return (u16)((u + 0x7fffu + ((u >> 16) & 1u)) >> 16);  // RNE
}
__device__ __forceinline__ float bf2f(u16 s) {
    return __builtin_bit_cast(float, (u32)s << 16);
}

// ---------------- init: zero comm buffers + flags (must run every launch) ----
__global__ void k_init(u64* comm, int* flags, int n_comm, int n_flags) {
    int i = blockIdx.x * blockDim.x + threadIdx.x;
    int stride = gridDim.x * blockDim.x;
    for (int k = i; k < n_comm; k += stride) comm[k] = 0ull;
    for (int k = i; k < n_flags; k += stride) flags[k] = 0;
}

// ---------------- fp32 -> bf16 convert (x) -----------------------------------
__global__ void k_f2bf(const float* __restrict__ src, u16* __restrict__ dst, int n4) {
    int i = blockIdx.x * blockDim.x + threadIdx.x;
    if (i >= n4) return;
    float4 v = ((const float4*)src)[i];
    u32 lo = (u32)f2bf(v.x) | ((u32)f2bf(v.y) << 16);
    u32 hi = (u32)f2bf(v.z) | ((u32)f2bf(v.w) << 16);
    ((uint2*)dst)[i] = make_uint2(lo, hi);
}

// ---------------- pack Wx into transposed, gate-permuted layout --------------
// dst[n][k] (N-major, [NGATE][K]) where n = dir*2048 + pcol,
// pcol = p*64 + w*16 + g*4 + uu  maps to original col = g*512 + (p*16 + w*4 + uu)
__global__ void k_pack_wxT(const float* __restrict__ Wf, const float* __restrict__ Wb,
                           u16* __restrict__ dst, int K, int klog /* log2(K/8) */) {
    int gid = blockIdx.x * blockDim.x + threadIdx.x;
    if (gid >= (NGATE << klog)) return;
    int n  = gid >> klog;
    int kc = gid & ((1 << klog) - 1);
    int dir = n >> 11, pcol = n & 2047;
    int p = pcol >> 6, w = (pcol >> 4) & 3, g = (pcol >> 2) & 3, uu = pcol & 3;
    int u = p * 16 + w * 4 + uu;
    int oc = g * 512 + u;
    const float* src = dir ? Wb : Wf;
    u16* d = dst + (size_t)n * K + kc * 8;
    #pragma unroll
    for (int j = 0; j < 8; j++) d[j] = f2bf(src[(size_t)(kc * 8 + j) * 2048 + oc]);
}

// ---------------- pack Wh into per-wave MFMA B-fragment order ----------------
// dst index = ((((dir*32+p)*4 + w)*16 + kk)*64 + lane)*8 + j
// value = Wh[k = kk*32 + (lane>>4)*8 + j][col = g*512 + (p*16 + w*4 + uu)],
//   with g = (lane&15)>>2, uu = lane&3.
__global__ void k_pack_whF(const float* __restrict__ Whf, const float* __restrict__ Whb,
                           u16* __restrict__ dst) {
    int gid = blockIdx.x * blockDim.x + threadIdx.x;   // 262144 total
    int lane = gid & 63, kk = (gid >> 6) & 15, w = (gid >> 10) & 3,
        p = (gid >> 12) & 31, dir = (gid >> 17) & 1;
    int col16 = lane & 15, g = col16 >> 2, uu = col16 & 3;
    int u = p * 16 + w * 4 + uu, oc = g * 512 + u;
    int kbase = kk * 32 + (lane >> 4) * 8;
    const float* src = dir ? Whb : Whf;
    u16* d = dst + (size_t)gid * 8;
    #pragma unroll
    for (int j = 0; j < 8; j++) d[j] = f2bf(src[(size_t)(kbase + j) * 2048 + oc]);
}

// ---------------- bf16 GEMM: C[M][NGATE] = A[M][K] @ BT[n][k]^T --------------
// 128x128 tile, BK=64, 4 waves (2x2), wave tile 64x64 (4x4 fragments 16x16x32)
template <int K>
__global__ __launch_bounds__(256) void k_gemm(const u16* __restrict__ A,
                                              const u16* __restrict__ BT,
                                              u16* __restrict__ C) {
    __shared__ __align__(16) u16 a_lds[128][72];
    __shared__ __align__(16) u16 b_lds[128][72];
    const int tid = threadIdx.x;
    const int lane = tid & 63;
    const int wav = tid >> 6;
    const int wr = wav >> 1, wc = wav & 1;
    const int row0 = blockIdx.y * 128, col0 = blockIdx.x * 128;
    const int r_ld = lane & 15;
    const int k_ld = (lane >> 4) * 8;
    f32x4 acc[4][4] = {};
    for (int kt = 0; kt < K; kt += 64) {
        __syncthreads();
        #pragma unroll
        for (int it = 0; it < 4; it++) {
            int c = tid + it * 256;
            int r = c >> 3, ko = (c & 7) * 8;
            *(short8*)&a_lds[r][ko] = *(const short8*)&A[(size_t)(row0 + r) * K + kt + ko];
            *(short8*)&b_lds[r][ko] = *(const short8*)&BT[(size_t)(col0 + r) * K + kt + ko];
        }
        __syncthreads();
        #pragma unroll
        for (int kk = 0; kk < 2; kk++) {
            short8 af[4], bfr[4];
            #pragma unroll
            for (int m = 0; m < 4; m++)
                af[m] = *(const short8*)&a_lds[wr * 64 + m * 16 + r_ld][kk * 32 + k_ld];
            #pragma unroll
            for (int n = 0; n < 4; n++)
                bfr[n] = *(const short8*)&b_lds[wc * 64 + n * 16 + r_ld][kk * 32 + k_ld];
            #pragma unroll
            for (int m = 0; m < 4; m++)
                #pragma unroll
                for (int n = 0; n < 4; n++)
                    acc[m][n] = __builtin_amdgcn_mfma_f32_16x16x32_bf16(af[m], bfr[n], acc[m][n], 0, 0, 0);
        }
    }
    const int rrow = (lane >> 4) * 4;
    const int rcol = lane & 15;
    #pragma unroll
    for (int m = 0; m < 4; m++)
        #pragma unroll
        for (int n = 0; n < 4; n++) {
            size_t rbase = (size_t)(row0 + wr * 64 + m * 16 + rrow);
            int col = col0 + wc * 64 + n * 16 + rcol;
            #pragma unroll
            for (int r = 0; r < 4; r++)
                C[(rbase + r) * NGATE + col] = f2bf(acc[m][n][r]);
        }
}

// ---------------- persistent LSTM scan (one layer, both directions) ----------
// grid = 64 blocks: dir = bid>>5, p = bid&31. Block owns hidden units
// [p*16, p*16+16) of its direction. h exchanged per step via agent-scope
// atomics in `comm` (double buffered), per-block monotonic flags.
__global__ __launch_bounds__(256) void k_scan(
    const u16* __restrict__ pre,      // [NTOK][NGATE] bf16 (token r = b*T + t)
    const u16* __restrict__ whF,      // this layer's packed Wh fragments
    const float* __restrict__ bias_f, const float* __restrict__ bias_b,
    u16* __restrict__ y_bf,           // layer0: y0 [NTOK][1024] bf16 (else null)
    float* __restrict__ y_f32,        // layer1: d_out [NTOK][1024] f32 (else null)
    u64* __restrict__ comm,           // [dir][2 buf][8 b][128 ull]
    int* __restrict__ flags)          // [dir][32] stride FSTR
{
    __shared__ __align__(16) u16  h_lds[8][520];
    __shared__ __align__(16) u16  z_pre[8][64];
    __shared__ __align__(16) float z_mm[8][64];
    __shared__ __align__(16) u16  h_loc[8][16];

    const int tid = threadIdx.x;
    const int dir = blockIdx.x >> 5;
    const int p   = blockIdx.x & 31;
    const int lane = tid & 63;
    const int w = tid >> 6;

    // preload B fragments (Wh slice) into registers: 16 x short8 = 64 VGPRs
    short8 bfrag[16];
    {
        const u16* base = whF + (size_t)((dir * PBLK + p) * 4 + w) * 8192 + (size_t)lane * 8;
        #pragma unroll
        for (int kk = 0; kk < 16; kk++) bfrag[kk] = *(const short8*)(base + kk * 512);
    }

    // elementwise thread state
    float c_st = 0.f, bi = 0.f, bff = 0.f, bg = 0.f, bo = 0.f;
    int eb = 0, ul = 0, ugl = 0;
    if (tid < 128) {
        eb = tid >> 4; ul = tid & 15; ugl = p * 16 + ul;
        const float* bias = dir ? bias_b : bias_f;
        bi = bias[ugl]; bff = bias[512 + ugl]; bg = bias[1024 + ugl]; bo = bias[1536 + ugl];
    }
    const int a_b = lane & 7;
    const int a_k = (lane >> 4) * 8;
    const int zrow_hi = lane >> 4;
    int* myflag  = flags + (dir * PBLK + (tid & 31)) * FSTR;
    int* ourflag = flags + (dir * PBLK + p) * FSTR;

    for (int s = 0; s < T_SEQ; s++) {
        const int t = dir ? (T_SEQ - 1 - s) : s;
        // (A) issue pre-activation load early (independent of recurrence)
        short8 preg;
        if (tid < 64) {
            int b = tid >> 3, seg = tid & 7;
            size_t r = (size_t)b * T_SEQ + t;
            preg = *(const short8*)&pre[r * NGATE + dir * 2048 + p * 64 + seg * 8];
        }
        asm volatile("" ::: "memory");
        // (B) wait for all producers of h[s-1]
        if (tid < PBLK) {
            while (__hip_atomic_load(myflag, __ATOMIC_ACQUIRE, __HIP_MEMORY_SCOPE_AGENT) < s)
                __builtin_amdgcn_s_sleep(1);
        }
        __syncthreads();
        // (D) pull full h[s-1] payload (agent-scope) into LDS
        {
            const u64* src = comm + ((size_t)dir * 2 + ((s & 1) ^ 1)) * 1024;
            #pragma unroll
            for (int q = 0; q < 4; q++) {
                int e = q * 256 + tid;                       // 0..1023
                u64 v = __hip_atomic_load(&src[e], __ATOMIC_RELAXED, __HIP_MEMORY_SCOPE_AGENT);
                int b = e >> 7, off = (e & 127) * 4;
                *(u64*)&h_lds[b][off] = v;
            }
        }
        if (tid < 64) {
            int b = tid >> 3, seg = tid & 7;
            *(short8*)&z_pre[b][seg * 8] = preg;
        }
        __syncthreads();
        // (F) z_mm = h[s-1] @ Wh  (two interleaved acc chains over 16 k-steps)
        {
            f32x4 acc0 = {}, acc1 = {};
            #pragma unroll
            for (int kk = 0; kk < 8; kk++) {
                short8 a0 = *(const short8*)&h_lds[a_b][kk * 32 + a_k];
                acc0 = __builtin_amdgcn_mfma_f32_16x16x32_bf16(a0, bfrag[kk], acc0, 0, 0, 0);
                short8 a1 = *(const short8*)&h_lds[a_b][(kk + 8) * 32 + a_k];
                acc1 = __builtin_amdgcn_mfma_f32_16x16x32_bf16(a1, bfrag[kk + 8], acc1, 0, 0, 0);
            }
            if (zrow_hi < 2) {
                #pragma unroll
                for (int r = 0; r < 4; r++)
                    z_mm[zrow_hi * 4 + r][w * 16 + (lane & 15)] = acc0[r] + acc1[r];
            }
        }
        __syncthreads();
        // (I) gates + state update + outputs (128 threads: 8 batches x 16 units)
        if (tid < 128) {
            int wu = ul >> 2, uq = ul & 3;
            int c0 = wu * 16 + uq;
            float zi = z_mm[eb][c0 + 0]  + bf2f(z_pre[eb][c0 + 0])  + bi;
            float zf = z_mm[eb][c0 + 4]  + bf2f(z_pre[eb][c0 + 4])  + bff;
            float zg = z_mm[eb][c0 + 8]  + bf2f(z_pre[eb][c0 + 8])  + bg;
            float zo = z_mm[eb][c0 + 12] + bf2f(z_pre[eb][c0 + 12]) + bo;
            float ig = 1.f / (1.f + __expf(-zi));
            float fg = 1.f / (1.f + __expf(-zf));
            float gg = tanhf(zg);
            float og = 1.f / (1.f + __expf(-zo));
            c_st = fg * c_st + ig * gg;
            float hv = og * tanhf(c_st);
            u16 hb16 = f2bf(hv);
            h_loc[eb][ul] = hb16;
            size_t r = (size_t)eb * T_SEQ + t;
            if (y_bf) y_bf[r * 1024 + dir * 512 + ugl] = hb16;
            else      y_f32[r * 1024 + dir * 512 + ugl] = hv;
        }
        __syncthreads();
        // (K) publish our h slice (agent-scope), fence, then flag
        if (tid < 32) {
            int b = tid >> 2, seg = tid & 3;
            u64 v = *(const u64*)&h_loc[b][seg * 4];
            u64* dst = comm + ((size_t)dir * 2 + (s & 1)) * 1024 + b * 128 + p * 4 + seg;
            __hip_atomic_store(dst, v, __ATOMIC_RELAXED, __HIP_MEMORY_SCOPE_AGENT);
            __threadfence();
        }
        __syncthreads();
        if (tid == 0)
            __hip_atomic_store(ourflag, s + 1, __ATOMIC_RELEASE, __HIP_MEMORY_SCOPE_AGENT);
    }
}

// ---------------- host launch -------------------------------------------------
extern "C" void kernel_launch(void* const* d_in, const int* in_sizes, int n_in,
                              void* d_out, int out_size, void* d_ws, size_t ws_size,
                              hipStream_t stream) {
    const float* x    = (const float*)d_in[0];
    const float* Wx0f = (const float*)d_in[1];
    const float* Wh0f = (const float*)d_in[2];
    const float* b0f  = (const float*)d_in[3];
    const float* Wx0b = (const float*)d_in[4];
    const float* Wh0b = (const float*)d_in[5];
    const float* b0b  = (const float*)d_in[6];
    const float* Wx1f = (const float*)d_in[7];
    const float* Wh1f = (const float*)d_in[8];
    const float* b1f  = (const float*)d_in[9];
    const float* Wx1b = (const float*)d_in[10];
    const float* Wh1b = (const float*)d_in[11];
    const float* b1b  = (const float*)d_in[12];
    float* out = (float*)d_out;

    char* ws = (char*)d_ws;
    size_t off = 0;
    auto take = [&](size_t bytes) {
        char* pp = ws + off;
        off = (off + bytes + 255) & ~(size_t)255;
        return pp;
    };
    u16* pre  = (u16*)take((size_t)NTOK * NGATE * 2);   // 134 MB (reused both layers)
    u16* x_bf = (u16*)take((size_t)NTOK * 512 * 2);     // 16 MB
    u16* y0   = (u16*)take((size_t)NTOK * 1024 * 2);    // 33 MB
    u16* wxT0 = (u16*)take((size_t)NGATE * 512 * 2);    // 4 MB
    u16* wxT1 = (u16*)take((size_t)NGATE * 1024 * 2);   // 8 MB
    u16* whF  = (u16*)take((size_t)2 * 2097152 * 2);    // 8 MB (2 layers)
    u64* comm = (u64*)take((size_t)2 * 4096 * 8);       // 64 KB
    int* flags = (int*)take((size_t)2 * 1024 * 4);      // 8 KB

    k_init<<<32, 256, 0, stream>>>(comm, flags, 2 * 4096, 2 * 1024);
    k_f2bf<<<8192, 256, 0, stream>>>(x, x_bf, NTOK * 512 / 4);
    k_pack_wxT<<<1024, 256, 0, stream>>>(Wx0f, Wx0b, wxT0, 512, 6);
    k_pack_wxT<<<2048, 256, 0, stream>>>(Wx1f, Wx1b, wxT1, 1024, 7);
    k_pack_whF<<<1024, 256, 0, stream>>>(Wh0f, Wh0b, whF);
    k_pack_whF<<<1024, 256, 0, stream>>>(Wh1f, Wh1b, whF + 2097152);

    // layer 0
    k_gemm<512><<<dim3(32, 128), 256, 0, stream>>>(x_bf, wxT0, pre);
    k_scan<<<64, 256, 0, stream>>>(pre, whF, b0f, b0b, y0, nullptr, comm, flags);
    // layer 1
    k_gemm<1024><<<dim3(32, 128), 256, 0, stream>>>(y0, wxT1, pre);
    k_scan<<<64, 256, 0, stream>>>(pre, whF + 2097152, b1f, b1b, nullptr, out,
                                   comm + 4096, flags + 1024);
}

// Round 2
// 12452.377 us; speedup vs baseline: 1.5903x; 1.5903x over previous
//
#include <hip/hip_runtime.h>
#include <hip/hip_bf16.h>
#include <stdint.h>

typedef unsigned short u16;
typedef unsigned int   u32;
typedef unsigned long long u64;
typedef __attribute__((ext_vector_type(8))) short short8;
typedef __attribute__((ext_vector_type(4))) float f32x4;

#define T_SEQ 2048
#define NTOK  16384        // B*T = 8*2048
#define NGATE 4096         // 2 dirs * 4H(=2048)
#define SBLK  8            // blocks per direction in the scan

__device__ __forceinline__ u16 f2bf(float f) {
    u32 u = __builtin_bit_cast(u32, f);
    return (u16)((u + 0x7fffu + ((u >> 16) & 1u)) >> 16);  // RNE
}
__device__ __forceinline__ float bf2f(u16 s) {
    return __builtin_bit_cast(float, (u32)s << 16);
}

// ---------------- init: zero comm buffers (tags=0 == initial h=0) ------------
__global__ void k_init(u32* comm, int n_comm) {
    int i = blockIdx.x * blockDim.x + threadIdx.x;
    int stride = gridDim.x * blockDim.x;
    for (int k = i; k < n_comm; k += stride) comm[k] = 0u;
}

// ---------------- fp32 -> bf16 convert (x) -----------------------------------
__global__ void k_f2bf(const float* __restrict__ src, u16* __restrict__ dst, int n4) {
    int i = blockIdx.x * blockDim.x + threadIdx.x;
    if (i >= n4) return;
    float4 v = ((const float4*)src)[i];
    u32 lo = (u32)f2bf(v.x) | ((u32)f2bf(v.y) << 16);
    u32 hi = (u32)f2bf(v.z) | ((u32)f2bf(v.w) << 16);
    ((uint2*)dst)[i] = make_uint2(lo, hi);
}

// ---------------- pack Wx into transposed, gate-permuted layout --------------
// dst[n][k] (N-major, [NGATE][K]) where n = dir*2048 + pcol,
// pcol maps: chunk c = pcol>>4, within-chunk col16 = pcol&15 -> g = col16>>2,
// uu = col16&3; hidden unit u = c*4+uu; original col = g*512 + u.
__global__ void k_pack_wxT(const float* __restrict__ Wf, const float* __restrict__ Wb,
                           u16* __restrict__ dst, int K, int klog /* log2(K/8) */) {
    int gid = blockIdx.x * blockDim.x + threadIdx.x;
    if (gid >= (NGATE << klog)) return;
    int n  = gid >> klog;
    int kc = gid & ((1 << klog) - 1);
    int dir = n >> 11, pcol = n & 2047;
    int c = pcol >> 4, g = (pcol >> 2) & 3, uu = pcol & 3;
    int u = c * 4 + uu;
    int oc = g * 512 + u;
    const float* src = dir ? Wb : Wf;
    u16* d = dst + (size_t)n * K + kc * 8;
    #pragma unroll
    for (int j = 0; j < 8; j++) d[j] = f2bf(src[(size_t)(kc * 8 + j) * 2048 + oc]);
}

// ---------------- pack Wh into per-wave MFMA B-fragment order ----------------
// dst index = (((dir*128 + c)*16 + kk)*64 + lane)*8 + j   (chunk c = pcol>>4)
// value = Wh[k = kk*32 + (lane>>4)*8 + j][col = g*512 + (c*4 + uu)],
//   with g = (lane&15)>>2, uu = lane&3.
__global__ void k_pack_whF(const float* __restrict__ Whf, const float* __restrict__ Whb,
                           u16* __restrict__ dst) {
    int gid = blockIdx.x * blockDim.x + threadIdx.x;   // 262144 total
    int lane = gid & 63, kk = (gid >> 6) & 15, c = (gid >> 10) & 127, dir = (gid >> 17) & 1;
    int col16 = lane & 15, g = col16 >> 2, uu = col16 & 3;
    int u = c * 4 + uu, oc = g * 512 + u;
    int kbase = kk * 32 + (lane >> 4) * 8;
    const float* src = dir ? Whb : Whf;
    u16* d = dst + (size_t)gid * 8;
    #pragma unroll
    for (int j = 0; j < 8; j++) d[j] = f2bf(src[(size_t)(kbase + j) * 2048 + oc]);
}

// ---------------- bf16 GEMM: C[M][NGATE] = A[M][K] @ BT[n][k]^T --------------
template <int K>
__global__ __launch_bounds__(256) void k_gemm(const u16* __restrict__ A,
                                              const u16* __restrict__ BT,
                                              u16* __restrict__ C) {
    __shared__ __align__(16) u16 a_lds[128][72];
    __shared__ __align__(16) u16 b_lds[128][72];
    const int tid = threadIdx.x;
    const int lane = tid & 63;
    const int wav = tid >> 6;
    const int wr = wav >> 1, wc = wav & 1;
    const int row0 = blockIdx.y * 128, col0 = blockIdx.x * 128;
    const int r_ld = lane & 15;
    const int k_ld = (lane >> 4) * 8;
    f32x4 acc[4][4] = {};
    for (int kt = 0; kt < K; kt += 64) {
        __syncthreads();
        #pragma unroll
        for (int it = 0; it < 4; it++) {
            int cc = tid + it * 256;
            int r = cc >> 3, ko = (cc & 7) * 8;
            *(short8*)&a_lds[r][ko] = *(const short8*)&A[(size_t)(row0 + r) * K + kt + ko];
            *(short8*)&b_lds[r][ko] = *(const short8*)&BT[(size_t)(col0 + r) * K + kt + ko];
        }
        __syncthreads();
        #pragma unroll
        for (int kk = 0; kk < 2; kk++) {
            short8 af[4], bfr[4];
            #pragma unroll
            for (int m = 0; m < 4; m++)
                af[m] = *(const short8*)&a_lds[wr * 64 + m * 16 + r_ld][kk * 32 + k_ld];
            #pragma unroll
            for (int n = 0; n < 4; n++)
                bfr[n] = *(const short8*)&b_lds[wc * 64 + n * 16 + r_ld][kk * 32 + k_ld];
            #pragma unroll
            for (int m = 0; m < 4; m++)
                #pragma unroll
                for (int n = 0; n < 4; n++)
                    acc[m][n] = __builtin_amdgcn_mfma_f32_16x16x32_bf16(af[m], bfr[n], acc[m][n], 0, 0, 0);
        }
    }
    const int rrow = (lane >> 4) * 4;
    const int rcol = lane & 15;
    #pragma unroll
    for (int m = 0; m < 4; m++)
        #pragma unroll
        for (int n = 0; n < 4; n++) {
            size_t rbase = (size_t)(row0 + wr * 64 + m * 16 + rrow);
            int col = col0 + wc * 64 + n * 16 + rcol;
            #pragma unroll
            for (int r = 0; r < 4; r++)
                C[(rbase + r) * NGATE + col] = f2bf(acc[m][n][r]);
        }
}

// ---------------- persistent LSTM scan (one layer, both directions) ----------
// grid = 16 blocks x 1024 threads: dir = bid>>3, p = bid&7. Block owns hidden
// units [p*64, p*64+64) of its direction (gate cols [p*256, p*256+256)).
// h exchanged per step via tagged u32 words (bf16 value | step_tag<<16),
// double-buffered, agent-scope relaxed atomics. No fences, no flags:
// the tag travels atomically with the value.
__global__ __launch_bounds__(1024) void k_scan(
    const u16* __restrict__ pre,      // [NTOK][NGATE] bf16 (token r = b*T + t)
    const u16* __restrict__ whF,      // this layer's packed Wh fragments
    const float* __restrict__ bias_f, const float* __restrict__ bias_b,
    u16* __restrict__ y_bf,           // layer0: y0 [NTOK][1024] bf16 (else null)
    float* __restrict__ y_f32,        // layer1: d_out [NTOK][1024] f32 (else null)
    u32* __restrict__ comm)           // [dir][2 buf][8 b][512 u] tagged words
{
    __shared__ __align__(16) u16   h_lds[8][520];
    __shared__ __align__(16) u16   z_pre[8][264];
    __shared__ __align__(16) float z_mm[8][260];

    const int tid = threadIdx.x;
    const int dir = (int)(blockIdx.x >> 3);
    const int p   = (int)(blockIdx.x & 7);
    const int lane = tid & 63;
    const int w = tid >> 6;   // wave 0..15, owns gate-col chunk w of block's 16

    // preload B fragments (Wh slice) into registers: 16 x short8 = 64 VGPRs
    short8 bfrag[16];
    {
        const u16* base = whF + (size_t)(dir * 128 + p * 16 + w) * 8192 + (size_t)lane * 8;
        #pragma unroll
        for (int kk = 0; kk < 16; kk++) bfrag[kk] = *(const short8*)(base + kk * 512);
    }

    // gate-thread state (tid < 512): (b, u) = (tid>>6, tid&63)
    float c_st = 0.f, bi = 0.f, bff = 0.f, bg = 0.f, bo = 0.f;
    const int gb = tid >> 6;        // batch (valid when tid<512)
    const int gu = tid & 63;        // local hidden unit
    const bool is_g = tid < 512;
    if (is_g) {
        int u = p * 64 + gu;
        const float* bias = dir ? bias_b : bias_f;
        bi = bias[u]; bff = bias[512 + u]; bg = bias[1024 + u]; bo = bias[1536 + u];
    }
    const int a_b = lane & 7;           // A-frag row (batch); rows 8-15 garbage, unused
    const int a_k = (lane >> 4) * 8;
    const int zrow_hi = lane >> 4;

    u32* const pubdst0 = comm + (size_t)dir * 2 * 4096 + (gb << 9) + p * 64 + gu;

    for (int s = 0; s < T_SEQ; s++) {
        const int t = dir ? (T_SEQ - 1 - s) : s;
        // (A) issue pre-activation load early (independent of recurrence)
        short8 preg;
        if (tid < 256) {
            int b = tid >> 5, seg = tid & 31;
            size_t r = (size_t)b * T_SEQ + t;
            preg = *(const short8*)&pre[r * NGATE + dir * 2048 + p * 256 + seg * 8];
        }
        asm volatile("" ::: "memory");
        // (B) spin directly on tagged h words of step s; stage into LDS
        {
            const u32* srcbuf = comm + ((size_t)dir * 2 + ((s + 1) & 1)) * 4096;
            const u32 want = (u32)s & 0xffffu;
            u32 v0 = __hip_atomic_load(&srcbuf[tid],        __ATOMIC_RELAXED, __HIP_MEMORY_SCOPE_AGENT);
            u32 v1 = __hip_atomic_load(&srcbuf[1024 + tid], __ATOMIC_RELAXED, __HIP_MEMORY_SCOPE_AGENT);
            u32 v2 = __hip_atomic_load(&srcbuf[2048 + tid], __ATOMIC_RELAXED, __HIP_MEMORY_SCOPE_AGENT);
            u32 v3 = __hip_atomic_load(&srcbuf[3072 + tid], __ATOMIC_RELAXED, __HIP_MEMORY_SCOPE_AGENT);
            while ((v0 >> 16) != want)
                v0 = __hip_atomic_load(&srcbuf[tid],        __ATOMIC_RELAXED, __HIP_MEMORY_SCOPE_AGENT);
            while ((v1 >> 16) != want)
                v1 = __hip_atomic_load(&srcbuf[1024 + tid], __ATOMIC_RELAXED, __HIP_MEMORY_SCOPE_AGENT);
            while ((v2 >> 16) != want)
                v2 = __hip_atomic_load(&srcbuf[2048 + tid], __ATOMIC_RELAXED, __HIP_MEMORY_SCOPE_AGENT);
            while ((v3 >> 16) != want)
                v3 = __hip_atomic_load(&srcbuf[3072 + tid], __ATOMIC_RELAXED, __HIP_MEMORY_SCOPE_AGENT);
            int e0 = tid, e1 = 1024 + tid, e2 = 2048 + tid, e3 = 3072 + tid;
            h_lds[e0 >> 9][e0 & 511] = (u16)v0;
            h_lds[e1 >> 9][e1 & 511] = (u16)v1;
            h_lds[e2 >> 9][e2 & 511] = (u16)v2;
            h_lds[e3 >> 9][e3 & 511] = (u16)v3;
        }
        if (tid < 256) {
            int b = tid >> 5, seg = tid & 31;
            *(short8*)&z_pre[b][seg * 8] = preg;
        }
        __syncthreads();
        // (D) z_mm = h[s-1] @ Wh for this wave's 16 gate cols
        {
            f32x4 acc0 = {}, acc1 = {};
            #pragma unroll
            for (int kk = 0; kk < 8; kk++) {
                short8 a0 = *(const short8*)&h_lds[a_b][kk * 32 + a_k];
                acc0 = __builtin_amdgcn_mfma_f32_16x16x32_bf16(a0, bfrag[kk], acc0, 0, 0, 0);
                short8 a1 = *(const short8*)&h_lds[a_b][(kk + 8) * 32 + a_k];
                acc1 = __builtin_amdgcn_mfma_f32_16x16x32_bf16(a1, bfrag[kk + 8], acc1, 0, 0, 0);
            }
            if (zrow_hi < 2) {
                #pragma unroll
                for (int r = 0; r < 4; r++)
                    z_mm[zrow_hi * 4 + r][w * 16 + (lane & 15)] = acc0[r] + acc1[r];
            }
        }
        __syncthreads();
        // (F) gates + state update + publish + output (512 threads: 8b x 64u)
        if (is_g) {
            int c0 = (gu >> 2) * 16 + (gu & 3);
            float zi = z_mm[gb][c0 + 0]  + bf2f(z_pre[gb][c0 + 0])  + bi;
            float zf = z_mm[gb][c0 + 4]  + bf2f(z_pre[gb][c0 + 4])  + bff;
            float zg = z_mm[gb][c0 + 8]  + bf2f(z_pre[gb][c0 + 8])  + bg;
            float zo = z_mm[gb][c0 + 12] + bf2f(z_pre[gb][c0 + 12]) + bo;
            float ig = 1.f / (1.f + __expf(-zi));
            float fg = 1.f / (1.f + __expf(-zf));
            float gg = 2.f / (1.f + __expf(-2.f * zg)) - 1.f;
            float og = 1.f / (1.f + __expf(-zo));
            c_st = fg * c_st + ig * gg;
            float th = 2.f / (1.f + __expf(-2.f * c_st)) - 1.f;
            float hv = og * th;
            u16 hb16 = f2bf(hv);
            // publish: value+tag in one atomic word, no fence needed
            u32 pw = (u32)hb16 | ((u32)((s + 1) & 0xffff) << 16);
            __hip_atomic_store(pubdst0 + (size_t)(s & 1) * 4096, pw,
                               __ATOMIC_RELAXED, __HIP_MEMORY_SCOPE_AGENT);
            size_t r = (size_t)gb * T_SEQ + t;
            if (y_bf) y_bf[r * 1024 + dir * 512 + p * 64 + gu] = hb16;
            else      y_f32[r * 1024 + dir * 512 + p * 64 + gu] = hv;
        }
        __syncthreads();
    }
}

// ---------------- host launch -------------------------------------------------
extern "C" void kernel_launch(void* const* d_in, const int* in_sizes, int n_in,
                              void* d_out, int out_size, void* d_ws, size_t ws_size,
                              hipStream_t stream) {
    const float* x    = (const float*)d_in[0];
    const float* Wx0f = (const float*)d_in[1];
    const float* Wh0f = (const float*)d_in[2];
    const float* b0f  = (const float*)d_in[3];
    const float* Wx0b = (const float*)d_in[4];
    const float* Wh0b = (const float*)d_in[5];
    const float* b0b  = (const float*)d_in[6];
    const float* Wx1f = (const float*)d_in[7];
    const float* Wh1f = (const float*)d_in[8];
    const float* b1f  = (const float*)d_in[9];
    const float* Wx1b = (const float*)d_in[10];
    const float* Wh1b = (const float*)d_in[11];
    const float* b1b  = (const float*)d_in[12];
    float* out = (float*)d_out;

    char* ws = (char*)d_ws;
    size_t off = 0;
    auto take = [&](size_t bytes) {
        char* pp = ws + off;
        off = (off + bytes + 255) & ~(size_t)255;
        return pp;
    };
    u16* pre  = (u16*)take((size_t)NTOK * NGATE * 2);   // 134 MB (reused both layers)
    u16* x_bf = (u16*)take((size_t)NTOK * 512 * 2);     // 16 MB
    u16* y0   = (u16*)take((size_t)NTOK * 1024 * 2);    // 33 MB
    u16* wxT0 = (u16*)take((size_t)NGATE * 512 * 2);    // 4 MB
    u16* wxT1 = (u16*)take((size_t)NGATE * 1024 * 2);   // 8 MB
    u16* whF  = (u16*)take((size_t)2 * 2097152 * 2);    // 8 MB (2 layers)
    u32* comm = (u32*)take((size_t)2 * 16384 * 4);      // 128 KB (2 layers)

    k_init<<<32, 256, 0, stream>>>(comm, 2 * 16384);
    k_f2bf<<<8192, 256, 0, stream>>>(x, x_bf, NTOK * 512 / 4);
    k_pack_wxT<<<1024, 256, 0, stream>>>(Wx0f, Wx0b, wxT0, 512, 6);
    k_pack_wxT<<<2048, 256, 0, stream>>>(Wx1f, Wx1b, wxT1, 1024, 7);
    k_pack_whF<<<1024, 256, 0, stream>>>(Wh0f, Wh0b, whF);
    k_pack_whF<<<1024, 256, 0, stream>>>(Wh1f, Wh1b, whF + 2097152);

    // layer 0
    k_gemm<512><<<dim3(32, 128), 256, 0, stream>>>(x_bf, wxT0, pre);
    k_scan<<<16, 1024, 0, stream>>>(pre, whF, b0f, b0b, y0, nullptr, comm);
    // layer 1
    k_gemm<1024><<<dim3(32, 128), 256, 0, stream>>>(y0, wxT1, pre);
    k_scan<<<16, 1024, 0, stream>>>(pre, whF + 2097152, b1f, b1b, nullptr, out,
                                    comm + 16384);
}